// Round 1
// baseline (2932.020 us; speedup 1.0000x reference)
//
#include <hip/hip_runtime.h>
#include <math.h>

// Problem constants (match reference)
#define NB   32
#define NA   24564
#define NTOT (NB * NA)
#define NCH  85        // 4 box deltas + 1 bg + 80 fg logits... actually 4 + 81 logits
#define TOPK 200
#define IOU_THR_F     0.5f
#define SCORE_FLOOR_F 0.01f

// ---------------------------------------------------------------------------
// Kernel 1: decode boxes + softmax score/cls per anchor.
// Strict IEEE f32 per-op (no contraction) via __f*_rn to match numpy ref;
// exp computed in double (correctly-rounded f32 on narrowing).
// ---------------------------------------------------------------------------
__global__ __launch_bounds__(256) void decode_kernel(
    const float* __restrict__ x, const float* __restrict__ anchor,
    float4* __restrict__ boxes, float* __restrict__ scores,
    float* __restrict__ clsf)
{
    int g = blockIdx.x * 256 + threadIdx.x;
    if (g >= NTOT) return;
    int i = g % NA;  // anchor index within batch
    const float* row = x + (long long)g * NCH;

    float ax = anchor[i * 4 + 0];
    float ay = anchor[i * 4 + 1];
    float aw = anchor[i * 4 + 2];
    float ah = anchor[i * 4 + 3];

    float d0 = row[0], d1 = row[1], d2 = row[2], d3 = row[3];
    // cx = d0*aw/10 + ax  (mul, div, add — no FMA contraction)
    float cx = __fadd_rn(__fdiv_rn(__fmul_rn(d0, aw), 10.0f), ax);
    float cy = __fadd_rn(__fdiv_rn(__fmul_rn(d1, ah), 10.0f), ay);
    // w = exp(d2/5)*aw ; exp via double = correctly-rounded f32
    float w = __fmul_rn((float)exp((double)__fdiv_rn(d2, 5.0f)), aw);
    float h = __fmul_rn((float)exp((double)__fdiv_rn(d3, 5.0f)), ah);
    float hw = __fmul_rn(w, 0.5f);  // w/2 exact
    float hh = __fmul_rn(h, 0.5f);
    boxes[g] = make_float4(__fsub_rn(cx, hw), __fsub_rn(cy, hh),
                           __fadd_rn(cx, hw), __fadd_rn(cy, hh));

    // softmax over 81 logits row[4..85): m = max; S = sum exp(z-m) (double);
    // score = exp(z_bestfg - m)/S ; cls = first-argmax over fg (strict >)
    const float* z = row + 4;
    float m = z[0];
    #pragma unroll 9
    for (int k = 1; k < 81; k++) m = fmaxf(m, z[k]);

    double S = 0.0;
    double be = 0.0;
    float  bz = -INFINITY;
    int    bj = 0;
    for (int k = 0; k < 81; k++) {
        float zk = z[k];
        double e = exp((double)__fsub_rn(zk, m));
        S += e;
        if (k >= 1 && zk > bz) { bz = zk; be = e; bj = k - 1; }
    }
    scores[g] = (float)(be / S);
    clsf[g]   = (float)bj;
}

// ---------------------------------------------------------------------------
// Kernel 2: per-batch greedy NMS. One workgroup (1024 thr) per batch.
// Scores live in LDS (98 KB); argmax via packed u64 key
// (score_bits<<32 | NA-idx) => max score, tie -> smallest index, matching
// stable argsort(-score) + first-valid semantics of the reference.
// Suppressed entries get score 0 (real scores are strictly positive).
// ---------------------------------------------------------------------------
__global__ __launch_bounds__(1024) void nms_kernel(
    const float4* __restrict__ boxes, const float* __restrict__ scores,
    const float* __restrict__ clsf, float* __restrict__ out)
{
    __shared__ float s_score[NA];                  // 98,256 B
    __shared__ unsigned long long s_red[16];
    __shared__ unsigned long long s_best;
    __shared__ float s_box[4];

    const int b   = blockIdx.x;
    const int tid = threadIdx.x;
    const float*  sc = scores + (long long)b * NA;
    const float4* bx = boxes  + (long long)b * NA;
    const float*  cf = clsf   + (long long)b * NA;
    float* ob = out + (long long)b * TOPK * 6;

    for (int j = tid; j < NA; j += 1024) s_score[j] = sc[j];
    __syncthreads();

    int t = 0;
    for (; t < TOPK; t++) {
        // ---- block argmax over packed keys ----
        unsigned long long best = 0ULL;
        for (int j = tid; j < NA; j += 1024) {
            float s = s_score[j];
            unsigned long long key =
                ((unsigned long long)__float_as_uint(s) << 32) |
                (unsigned int)(NA - j);
            if (key > best) best = key;
        }
        #pragma unroll
        for (int off = 32; off > 0; off >>= 1) {
            unsigned long long o = __shfl_down(best, off, 64);
            if (o > best) best = o;
        }
        if ((tid & 63) == 0) s_red[tid >> 6] = best;
        __syncthreads();
        if (tid == 0) {
            unsigned long long mb = s_red[0];
            #pragma unroll
            for (int wv = 1; wv < 16; wv++)
                if (s_red[wv] > mb) mb = s_red[wv];
            s_best = mb;
        }
        __syncthreads();
        best = s_best;

        float bscore = __uint_as_float((unsigned int)(best >> 32));
        int   bidx   = NA - (int)(best & 0xFFFFFFFFu);

        if (!(bscore >= SCORE_FLOOR_F)) break;   // exhausted or below floor

        if (tid == 0) {
            float4 v = bx[bidx];
            s_box[0] = v.x; s_box[1] = v.y; s_box[2] = v.z; s_box[3] = v.w;
            ob[t * 6 + 0] = cf[bidx];
            ob[t * 6 + 1] = bscore;
            ob[t * 6 + 2] = v.x;
            ob[t * 6 + 3] = v.y;
            ob[t * 6 + 4] = v.z;
            ob[t * 6 + 5] = v.w;
            s_score[bidx] = 0.0f;   // explicit self-invalidate (ref .at[idx].set(False))
        }
        __syncthreads();

        // ---- suppression pass: IoU(chosen, all still-valid) ----
        const float b1x1 = s_box[0], b1y1 = s_box[1];
        const float b1x2 = s_box[2], b1y2 = s_box[3];
        const float area1 = __fmul_rn(__fsub_rn(b1x2, b1x1), __fsub_rn(b1y2, b1y1));
        for (int j = tid; j < NA; j += 1024) {
            if (s_score[j] > 0.0f) {
                float4 v = bx[j];
                float area2 = __fmul_rn(__fsub_rn(v.z, v.x), __fsub_rn(v.w, v.y));
                float xl = fmaxf(b1x1, v.x);
                float xr = fminf(b1x2, v.z);
                float yt = fmaxf(b1y1, v.y);
                float yb = fminf(b1y2, v.w);
                float cw = fminf(fmaxf(__fsub_rn(xr, xl), 0.0f), 1.0f);
                float ch = fminf(fmaxf(__fsub_rn(yb, yt), 0.0f), 1.0f);
                float common = __fmul_rn(cw, ch);
                float denom  = __fsub_rn(__fadd_rn(area1, area2), common);
                float iou    = __fdiv_rn(common, denom);
                if (!(iou < IOU_THR_F)) s_score[j] = 0.0f;
            }
        }
        __syncthreads();
    }

    // zero-fill remaining rows (reference emits zeros once exhausted/below floor)
    for (int k = t * 6 + tid; k < TOPK * 6; k += 1024) ob[k] = 0.0f;
}

// ---------------------------------------------------------------------------
extern "C" void kernel_launch(void* const* d_in, const int* in_sizes, int n_in,
                              void* d_out, int out_size, void* d_ws, size_t ws_size,
                              hipStream_t stream) {
    const float* x      = (const float*)d_in[0];   // (32, 24564, 85)
    const float* anchor = (const float*)d_in[1];   // (24564, 4)
    float* out = (float*)d_out;                    // (32, 200, 6)

    char* ws = (char*)d_ws;
    const size_t boxes_bytes  = (size_t)NTOT * 16;          // 12,576,768
    const size_t scores_off   = (boxes_bytes + 255) & ~255ULL;
    const size_t scores_bytes = (size_t)NTOT * 4;           // 3,144,192
    const size_t cls_off      = (scores_off + scores_bytes + 255) & ~255ULL;

    float4* boxes  = (float4*)ws;
    float*  scores = (float*)(ws + scores_off);
    float*  clsf   = (float*)(ws + cls_off);

    int blocks = (NTOT + 255) / 256;
    decode_kernel<<<blocks, 256, 0, stream>>>(x, anchor, boxes, scores, clsf);
    nms_kernel<<<NB, 1024, 0, stream>>>(boxes, scores, clsf, out);
}